// Round 5
// baseline (92.248 us; speedup 1.0000x reference)
//
#include <hip/hip_runtime.h>
#include <math.h>

#define N_ROWS 8192
#define HDIM   1024
#define KK     10
#define EPSF   1e-8f
#define NBLK   256
#define TPB    512              // 8 waves/block, 1 block/CU
#define WPB    (TPB / 64)
#define RPW    4                // rows per wave (register-blocked)

// VALU-pipe wave64 all-reduce via DPP; DS pipe stays reserved for center reads.
#define DPP_ADD(x, ctrl, rmask, bmask)                                        \
    x += __int_as_float(__builtin_amdgcn_update_dpp(                          \
        0, __float_as_int(x), ctrl, rmask, bmask, true))

__device__ __forceinline__ float wave_allreduce_add(float x) {
    DPP_ADD(x, 0x111, 0xf, 0xf);  // row_shr:1
    DPP_ADD(x, 0x112, 0xf, 0xf);  // row_shr:2
    DPP_ADD(x, 0x114, 0xf, 0xe);  // row_shr:4
    DPP_ADD(x, 0x118, 0xf, 0xc);  // row_shr:8
    DPP_ADD(x, 0x142, 0xa, 0xf);  // row_bcast:15
    DPP_ADD(x, 0x143, 0xc, 0xf);  // row_bcast:31
    return __int_as_float(__builtin_amdgcn_readlane(__float_as_int(x), 63));
}

// Fused: LDS-staged centers (40 KB/block), 4 rows/wave register-blocked,
// last-finishing block does the 256-partial reduction (saves the tail
// kernel dispatch + node gap; R3 proved the handoff itself costs ~0 and is
// cross-XCD-correct with agent-scope atomics).
//
// NOTE (R4 analysis): three different kernel designs all ran ~30 us because
// the harness's 256 MiB d_ws poison drains to HBM while we execute AND
// evicts x from L3 — our reads run at a contended ~1.1 TB/s share. Kernel
// time is set by HBM contention, not by our pipes; the only remaining
// controllable cost was the tail dispatch, fused here.
__global__ __launch_bounds__(TPB, 2)
void knife_fused(const float* __restrict__ x,
                 const float* __restrict__ centers,
                 const float* __restrict__ weights,
                 const float* __restrict__ scales,
                 float* __restrict__ partials,
                 unsigned int* __restrict__ counter,
                 float* __restrict__ out) {
    const int lane = threadIdx.x & 63;
    const int wid  = threadIdx.x >> 6;

    __shared__ float4 cs[KK * (HDIM / 4)];   // 40960 B

    // Stage centers: coalesced thread-stride copy (5 float4/thread).
    const float4* c4 = (const float4*)centers;
    for (int i = threadIdx.x; i < KK * (HDIM / 4); i += TPB)
        cs[i] = c4[i];

    float w[KK], inv2s2[KK];
#pragma unroll
    for (int k = 0; k < KK; ++k) {
        w[k] = weights[k];
        float sc = scales[k];
        inv2s2[k] = 1.0f / (2.0f * sc * sc);
    }

    // Issue this wave's 4 rows of x (16 b128, 16 KB in flight) so HBM
    // latency overlaps the staging barrier + csq work.
    const int g  = blockIdx.x * WPB + wid;       // 0..2047
    const int r0 = g * RPW;
    const float4* xr = (const float4*)x + ((size_t)r0 << 8);
    float4 xv[RPW][4];
#pragma unroll
    for (int r = 0; r < RPW; ++r)
#pragma unroll
        for (int j = 0; j < 4; ++j)
            xv[r][j] = xr[(size_t)r * 256 + lane + 64 * j];

    __syncthreads();

    // ||c_k||^2 (wave-uniform -> SGPR via readlane)
    float csq[KK];
#pragma unroll
    for (int k = 0; k < KK; ++k) {
        float s = 0.f;
#pragma unroll
        for (int j = 0; j < 4; ++j) {
            float4 v = cs[k * 256 + lane + 64 * j];
            s += v.x * v.x + v.y * v.y + v.z * v.z + v.w * v.w;
        }
        csq[k] = wave_allreduce_add(s);
    }

    // Main FMA: each center fragment read once from LDS, reused for 4 rows.
    float acc[RPW][KK + 1];
#pragma unroll
    for (int r = 0; r < RPW; ++r)
#pragma unroll
        for (int k = 0; k <= KK; ++k) acc[r][k] = 0.f;

#pragma unroll
    for (int j = 0; j < 4; ++j) {
#pragma unroll
        for (int r = 0; r < RPW; ++r) {
            float4 v = xv[r][j];
            acc[r][KK] += v.x * v.x + v.y * v.y + v.z * v.z + v.w * v.w;
        }
#pragma unroll
        for (int k = 0; k < KK; ++k) {
            float4 cv = cs[k * 256 + lane + 64 * j];   // ds_read_b128, x4 reuse
#pragma unroll
            for (int r = 0; r < RPW; ++r) {
                float4 v = xv[r][j];
                acc[r][k] += v.x * cv.x + v.y * cv.y + v.z * cv.z + v.w * cv.w;
            }
        }
    }

    // 44 independent DPP chains pipeline on the VALU; then density/log.
    float logsum = 0.f;
#pragma unroll
    for (int r = 0; r < RPW; ++r) {
        float xsq = wave_allreduce_add(acc[r][KK]);
        float density = 0.f;
#pragma unroll
        for (int k = 0; k < KK; ++k) {
            float dot = wave_allreduce_add(acc[r][k]);
            float d = fmaxf(xsq + csq[k] - 2.0f * dot, 0.0f);
            density += w[k] * __expf(-d * inv2s2[k]);
        }
        logsum += __logf(density + EPSF);
    }

    // Block partial -> global (agent scope), last-arriving block reduces.
    __shared__ float red[WPB];
    __shared__ int flag;
    if (lane == 0) red[wid] = logsum;
    __syncthreads();
    if (threadIdx.x == 0) {
        float v = 0.f;
#pragma unroll
        for (int i = 0; i < WPB; ++i) v += red[i];
        __hip_atomic_store(&partials[blockIdx.x], v,
                           __ATOMIC_RELEASE, __HIP_MEMORY_SCOPE_AGENT);
        unsigned int old = __hip_atomic_fetch_add(
            counter, 1u, __ATOMIC_ACQ_REL, __HIP_MEMORY_SCOPE_AGENT);
        flag = (old == NBLK - 1) ? 1 : 0;
    }
    __syncthreads();
    if (flag && wid == 0) {
        // Wave 0 of the last block: 4 partials per lane, agent-scope loads
        // (bypass stale per-XCD L2 lines), one DPP all-reduce, write out.
        float s = 0.f;
#pragma unroll
        for (int i = 0; i < 4; ++i)
            s += __hip_atomic_load(&partials[lane * 4 + i], __ATOMIC_ACQUIRE,
                                   __HIP_MEMORY_SCOPE_AGENT);
        s = wave_allreduce_add(s);
        if (lane == 0) {
            float h = -s / (float)N_ROWS;   // h_entropy
            out[0] = h;           // entropy_loss (BETA=1)
            out[1] = h * h;       // target_entropy_loss (TARGET=0)
            out[2] = h + h * h;   // total_loss
            out[3] = h;           // h_entropy
        }
    }
}

extern "C" void kernel_launch(void* const* d_in, const int* in_sizes, int n_in,
                              void* d_out, int out_size, void* d_ws, size_t ws_size,
                              hipStream_t stream) {
    const float* x       = (const float*)d_in[0];
    const float* centers = (const float*)d_in[1];
    const float* weights = (const float*)d_in[2];
    const float* scales  = (const float*)d_in[3];
    float* out      = (float*)d_out;
    float* partials = (float*)d_ws;                          // 256 floats
    unsigned int* counter = (unsigned int*)((char*)d_ws + 1024);

    // Deterministic counter init (graph-capturable async memset).
    hipMemsetAsync(counter, 0, sizeof(unsigned int), stream);
    knife_fused<<<NBLK, TPB, 0, stream>>>(x, centers, weights, scales,
                                          partials, counter, out);
}

// Round 6
// 92.024 us; speedup vs baseline: 1.0024x; 1.0024x over previous
//
#include <hip/hip_runtime.h>
#include <math.h>

#define N_ROWS 8192
#define HDIM   1024
#define KK     10
#define EPSF   1e-8f
#define NBLK   512
#define TPB    256              // 4 waves/block, 2 blocks/CU
#define WPB    (TPB / 64)
#define RPW    4                // rows per wave (register-blocked)

// VALU-pipe wave64 all-reduce via DPP; DS pipe stays reserved for center reads.
#define DPP_ADD(x, ctrl, rmask, bmask)                                        \
    x += __int_as_float(__builtin_amdgcn_update_dpp(                          \
        0, __float_as_int(x), ctrl, rmask, bmask, true))

__device__ __forceinline__ float wave_allreduce_add(float x) {
    DPP_ADD(x, 0x111, 0xf, 0xf);  // row_shr:1
    DPP_ADD(x, 0x112, 0xf, 0xf);  // row_shr:2
    DPP_ADD(x, 0x114, 0xf, 0xe);  // row_shr:4
    DPP_ADD(x, 0x118, 0xf, 0xc);  // row_shr:8
    DPP_ADD(x, 0x142, 0xa, 0xf);  // row_bcast:15
    DPP_ADD(x, 0x143, 0xc, 0xf);  // row_bcast:31
    return __int_as_float(__builtin_amdgcn_readlane(__float_as_int(x), 63));
}

// R4 structure (best known: 87.1 us), re-gridded 512x256: 2 blocks/CU so one
// block's staging barrier overlaps the other's compute; 4-wave barriers are
// cheaper than 8-wave; x loads issued BEFORE center staging so the per-wave
// 16 KB critical path heads the memory queue.
// (R5 lesson: last-block fusion costs +5 us on this harness — two kernels.)
__global__ __launch_bounds__(TPB, 2)
void knife_main(const float* __restrict__ x,
                const float* __restrict__ centers,
                const float* __restrict__ weights,
                const float* __restrict__ scales,
                float* __restrict__ partials) {
    const int lane = threadIdx.x & 63;
    const int wid  = threadIdx.x >> 6;

    __shared__ float4 cs[KK * (HDIM / 4)];   // 40960 B

    // x loads first: this wave's 4 rows (16 b128, 16 KB in flight).
    const int g  = blockIdx.x * WPB + wid;       // 0..2047
    const int r0 = g * RPW;
    const float4* xr = (const float4*)x + ((size_t)r0 << 8);
    float4 xv[RPW][4];
#pragma unroll
    for (int r = 0; r < RPW; ++r)
#pragma unroll
        for (int j = 0; j < 4; ++j)
            xv[r][j] = xr[(size_t)r * 256 + lane + 64 * j];

    // Stage centers: coalesced thread-stride copy (10 float4/thread).
    const float4* c4 = (const float4*)centers;
    for (int i = threadIdx.x; i < KK * (HDIM / 4); i += TPB)
        cs[i] = c4[i];

    float w[KK], inv2s2[KK];
#pragma unroll
    for (int k = 0; k < KK; ++k) {
        w[k] = weights[k];
        float sc = scales[k];
        inv2s2[k] = 1.0f / (2.0f * sc * sc);
    }

    __syncthreads();

    // ||c_k||^2 (wave-uniform -> SGPR via readlane)
    float csq[KK];
#pragma unroll
    for (int k = 0; k < KK; ++k) {
        float s = 0.f;
#pragma unroll
        for (int j = 0; j < 4; ++j) {
            float4 v = cs[k * 256 + lane + 64 * j];
            s += v.x * v.x + v.y * v.y + v.z * v.z + v.w * v.w;
        }
        csq[k] = wave_allreduce_add(s);
    }

    // Main FMA: each center fragment read once from LDS, reused for 4 rows.
    float acc[RPW][KK + 1];
#pragma unroll
    for (int r = 0; r < RPW; ++r)
#pragma unroll
        for (int k = 0; k <= KK; ++k) acc[r][k] = 0.f;

#pragma unroll
    for (int j = 0; j < 4; ++j) {
#pragma unroll
        for (int r = 0; r < RPW; ++r) {
            float4 v = xv[r][j];
            acc[r][KK] += v.x * v.x + v.y * v.y + v.z * v.z + v.w * v.w;
        }
#pragma unroll
        for (int k = 0; k < KK; ++k) {
            float4 cv = cs[k * 256 + lane + 64 * j];   // ds_read_b128, x4 reuse
#pragma unroll
            for (int r = 0; r < RPW; ++r) {
                float4 v = xv[r][j];
                acc[r][k] += v.x * cv.x + v.y * cv.y + v.z * cv.z + v.w * cv.w;
            }
        }
    }

    // 44 independent DPP chains pipeline on the VALU; then density/log.
    float logsum = 0.f;
#pragma unroll
    for (int r = 0; r < RPW; ++r) {
        float xsq = wave_allreduce_add(acc[r][KK]);
        float density = 0.f;
#pragma unroll
        for (int k = 0; k < KK; ++k) {
            float dot = wave_allreduce_add(acc[r][k]);
            float d = fmaxf(xsq + csq[k] - 2.0f * dot, 0.0f);
            density += w[k] * __expf(-d * inv2s2[k]);
        }
        logsum += __logf(density + EPSF);
    }

    __shared__ float red[WPB];
    if (lane == 0) red[wid] = logsum;
    __syncthreads();
    if (threadIdx.x == 0) {
        float t = 0.f;
#pragma unroll
        for (int i = 0; i < WPB; ++i) t += red[i];
        partials[blockIdx.x] = t;
    }
}

// Deterministic final reduction of 512 block partials + output assembly.
__global__ __launch_bounds__(256)
void knife_final(const float* __restrict__ partials, float* __restrict__ out) {
    __shared__ float red[4];
    int t = threadIdx.x;
    float s = partials[t] + partials[t + 256];
    s = wave_allreduce_add(s);
    if ((t & 63) == 0) red[t >> 6] = s;
    __syncthreads();
    if (t == 0) {
        float total = red[0] + red[1] + red[2] + red[3];
        float h = -total / (float)N_ROWS;   // h_entropy
        out[0] = h;           // entropy_loss (BETA=1)
        out[1] = h * h;       // target_entropy_loss (TARGET=0)
        out[2] = h + h * h;   // total_loss
        out[3] = h;           // h_entropy
    }
}

extern "C" void kernel_launch(void* const* d_in, const int* in_sizes, int n_in,
                              void* d_out, int out_size, void* d_ws, size_t ws_size,
                              hipStream_t stream) {
    const float* x       = (const float*)d_in[0];
    const float* centers = (const float*)d_in[1];
    const float* weights = (const float*)d_in[2];
    const float* scales  = (const float*)d_in[3];
    float* out      = (float*)d_out;
    float* partials = (float*)d_ws;   // 512 floats

    knife_main<<<NBLK, TPB, 0, stream>>>(x, centers, weights, scales, partials);
    knife_final<<<1, 256, 0, stream>>>(partials, out);
}

// Round 7
// 88.698 us; speedup vs baseline: 1.0400x; 1.0375x over previous
//
#include <hip/hip_runtime.h>
#include <math.h>

#define N_ROWS 8192
#define HDIM   1024
#define KK     10
#define EPSF   1e-8f
#define NBLK   256
#define TPB    512              // 8 waves/block, 1 block/CU — best measured (R4: 87.1 us)
#define WPB    (TPB / 64)
#define RPW    4                // rows per wave (register-blocked)

// VALU-pipe wave64 all-reduce via DPP; DS pipe stays reserved for center reads.
#define DPP_ADD(x, ctrl, rmask, bmask)                                        \
    x += __int_as_float(__builtin_amdgcn_update_dpp(                          \
        0, __float_as_int(x), ctrl, rmask, bmask, true))

__device__ __forceinline__ float wave_allreduce_add(float x) {
    DPP_ADD(x, 0x111, 0xf, 0xf);  // row_shr:1
    DPP_ADD(x, 0x112, 0xf, 0xf);  // row_shr:2
    DPP_ADD(x, 0x114, 0xf, 0xe);  // row_shr:4
    DPP_ADD(x, 0x118, 0xf, 0xc);  // row_shr:8
    DPP_ADD(x, 0x142, 0xa, 0xf);  // row_bcast:15
    DPP_ADD(x, 0x143, 0xc, 0xf);  // row_bcast:31
    return __int_as_float(__builtin_amdgcn_readlane(__float_as_int(x), 63));
}

// Best-measured configuration (R4 = 87.1 us). Session ledger:
//  - R3 (global center reloads, VGPR=104): kernel row 46.3 us -> fixed
//    harness cost ~54 us (256 MiB ws poison + 67 MB input restore, in-window).
//  - R2/R4/R6: three different kernel structures all ~87-92 us -> our ~33 us
//    share is HBM-contention-bound (poison write-drain + L3 eviction of x),
//    not kernel-structure-bound.
//  - R5 last-block fusion: +5.2 us (agent-scope RMW sweep). Reverted.
//  - R6 regrid 512x256: +4.9 us. Reverted.
__global__ __launch_bounds__(TPB, 2)
void knife_main(const float* __restrict__ x,
                const float* __restrict__ centers,
                const float* __restrict__ weights,
                const float* __restrict__ scales,
                float* __restrict__ partials) {
    const int lane = threadIdx.x & 63;
    const int wid  = threadIdx.x >> 6;

    __shared__ float4 cs[KK * (HDIM / 4)];   // 40960 B

    // Stage centers: coalesced thread-stride copy (5 float4/thread).
    const float4* c4 = (const float4*)centers;
    for (int i = threadIdx.x; i < KK * (HDIM / 4); i += TPB)
        cs[i] = c4[i];

    float w[KK], inv2s2[KK];
#pragma unroll
    for (int k = 0; k < KK; ++k) {
        w[k] = weights[k];
        float sc = scales[k];
        inv2s2[k] = 1.0f / (2.0f * sc * sc);
    }

    // This wave's 4 rows of x (16 b128, 16 KB in flight) overlap the
    // staging barrier + csq work.
    const int g  = blockIdx.x * WPB + wid;       // 0..2047
    const int r0 = g * RPW;
    const float4* xr = (const float4*)x + ((size_t)r0 << 8);
    float4 xv[RPW][4];
#pragma unroll
    for (int r = 0; r < RPW; ++r)
#pragma unroll
        for (int j = 0; j < 4; ++j)
            xv[r][j] = xr[(size_t)r * 256 + lane + 64 * j];

    __syncthreads();

    // ||c_k||^2 (wave-uniform -> SGPR via readlane)
    float csq[KK];
#pragma unroll
    for (int k = 0; k < KK; ++k) {
        float s = 0.f;
#pragma unroll
        for (int j = 0; j < 4; ++j) {
            float4 v = cs[k * 256 + lane + 64 * j];
            s += v.x * v.x + v.y * v.y + v.z * v.z + v.w * v.w;
        }
        csq[k] = wave_allreduce_add(s);
    }

    // Main FMA: each center fragment read once from LDS, reused for 4 rows.
    float acc[RPW][KK + 1];
#pragma unroll
    for (int r = 0; r < RPW; ++r)
#pragma unroll
        for (int k = 0; k <= KK; ++k) acc[r][k] = 0.f;

#pragma unroll
    for (int j = 0; j < 4; ++j) {
#pragma unroll
        for (int r = 0; r < RPW; ++r) {
            float4 v = xv[r][j];
            acc[r][KK] += v.x * v.x + v.y * v.y + v.z * v.z + v.w * v.w;
        }
#pragma unroll
        for (int k = 0; k < KK; ++k) {
            float4 cv = cs[k * 256 + lane + 64 * j];   // ds_read_b128, x4 reuse
#pragma unroll
            for (int r = 0; r < RPW; ++r) {
                float4 v = xv[r][j];
                acc[r][k] += v.x * cv.x + v.y * cv.y + v.z * cv.z + v.w * cv.w;
            }
        }
    }

    // 44 independent DPP chains pipeline on the VALU; then density/log.
    float logsum = 0.f;
#pragma unroll
    for (int r = 0; r < RPW; ++r) {
        float xsq = wave_allreduce_add(acc[r][KK]);
        float density = 0.f;
#pragma unroll
        for (int k = 0; k < KK; ++k) {
            float dot = wave_allreduce_add(acc[r][k]);
            float d = fmaxf(xsq + csq[k] - 2.0f * dot, 0.0f);
            density += w[k] * __expf(-d * inv2s2[k]);
        }
        logsum += __logf(density + EPSF);
    }

    __shared__ float red[WPB];
    if (lane == 0) red[wid] = logsum;
    __syncthreads();
    if (threadIdx.x == 0) {
        float t = 0.f;
#pragma unroll
        for (int i = 0; i < WPB; ++i) t += red[i];
        partials[blockIdx.x] = t;
    }
}

// Deterministic final reduction of 256 block partials + output assembly.
__global__ __launch_bounds__(256)
void knife_final(const float* __restrict__ partials, float* __restrict__ out) {
    __shared__ float red[4];
    int t = threadIdx.x;
    float s = partials[t];
    s = wave_allreduce_add(s);
    if ((t & 63) == 0) red[t >> 6] = s;
    __syncthreads();
    if (t == 0) {
        float total = red[0] + red[1] + red[2] + red[3];
        float h = -total / (float)N_ROWS;   // h_entropy
        out[0] = h;           // entropy_loss (BETA=1)
        out[1] = h * h;       // target_entropy_loss (TARGET=0)
        out[2] = h + h * h;   // total_loss
        out[3] = h;           // h_entropy
    }
}

extern "C" void kernel_launch(void* const* d_in, const int* in_sizes, int n_in,
                              void* d_out, int out_size, void* d_ws, size_t ws_size,
                              hipStream_t stream) {
    const float* x       = (const float*)d_in[0];
    const float* centers = (const float*)d_in[1];
    const float* weights = (const float*)d_in[2];
    const float* scales  = (const float*)d_in[3];
    float* out      = (float*)d_out;
    float* partials = (float*)d_ws;   // 256 floats

    knife_main<<<NBLK, TPB, 0, stream>>>(x, centers, weights, scales, partials);
    knife_final<<<1, 256, 0, stream>>>(partials, out);
}